// Round 5
// baseline (215.004 us; speedup 1.0000x reference)
//
#include <hip/hip_runtime.h>

typedef unsigned short ushort_t;
typedef __attribute__((ext_vector_type(8))) short bf16x8;
typedef __attribute__((ext_vector_type(4))) float f32x4;
typedef __attribute__((ext_vector_type(4))) unsigned short ushort4v;

// Problem constants
constexpr int BATCH = 32, CIN = 128, H = 56, W = 56, COUT = 256;
constexpr int HP = 58, WP = 58;
constexpr int KTOT = CIN * 9;                                        // 1152
constexpr size_t WB_BYTES = (size_t)COUT * KTOT * 2;                 // 589824
// xp2 chunk-major: [c8=16][b=32][h=58][w=58][8ch]
constexpr int PLANE = BATCH * HP * WP;                               // 107648 chunks per c8
constexpr size_t XP_BYTES = (size_t)16 * PLANE * 8 * 2;              // 27,557,888

__device__ inline ushort_t f2bf(float f) {
  union { float fl; unsigned u; } v; v.fl = f;
  unsigned u = v.u;
  return (ushort_t)((u + 0x7fffu + ((u >> 16) & 1u)) >> 16);  // RNE
}

// ---------------- pre-pass kernels ----------------

// W [256][128][3][3] f32 -> Wb2 [t=18][kblk=8][cout=256][8] bf16
// (t = pos*2+half; cin = half*64 + kblk*8 + c)
__global__ void conv_w(const float* __restrict__ Ws, ushort_t* __restrict__ Wb2) {
  int idx = blockIdx.x * 256 + threadIdx.x;      // < 294912
  int c = idx & 7;
  int cout = (idx >> 3) & 255;
  int kb = (idx >> 11) & 7;
  int t = idx >> 14;                             // 0..17
  int pos = t >> 1, half = t & 1;
  int cin = half * 64 + kb * 8 + c;
  Wb2[idx] = f2bf(Ws[(cout * 128 + cin) * 9 + pos]);
}

// x NCHW f32 -> xp2 [c8][b][h][w][8] bf16, ring zeros written here too.
__global__ void xpad2(const float* __restrict__ x, ushort_t* __restrict__ xp2) {
  __shared__ ushort_t tile[128][58];             // [c][w_padded]
  int bh = blockIdx.x;                           // 0..32*58-1
  int b = bh / 58, h = bh - b * 58;              // h padded 0..57
  bool interior = (h >= 1 && h <= 56);
  if (interior) {
    int hIn = h - 1;
    const float4* x4 = (const float4*)x;
    {  // zero pad columns
      int ch = threadIdx.x & 127, side = threadIdx.x >> 7;
      tile[ch][side * 57] = 0;
    }
    for (int it = 0; it < 7; ++it) {
      int i = it * 256 + (int)threadIdx.x;       // < 1792 = 128ch * 14
      int ch = i / 14, q = i - ch * 14;
      float4 v = x4[(size_t)(b * 128 + ch) * 784 + hIn * 14 + q];
      int wb = 1 + q * 4;
      tile[ch][wb + 0] = f2bf(v.x);
      tile[ch][wb + 1] = f2bf(v.y);
      tile[ch][wb + 2] = f2bf(v.z);
      tile[ch][wb + 3] = f2bf(v.w);
    }
  }
  __syncthreads();
  ushort4v* o4 = (ushort4v*)xp2;
  for (int it = 0; it < 8; ++it) {
    int i = it * 256 + (int)threadIdx.x;
    if (i >= 1856) break;                        // 16 c8 * 116 ushort4
    int c8 = i / 116, r = i - c8 * 116;
    int w = r >> 1, hf = r & 1;
    ushort4v v;
    if (interior) {
      int ch = c8 * 8 + hf * 4;
      v.x = tile[ch + 0][w];
      v.y = tile[ch + 1][w];
      v.z = tile[ch + 2][w];
      v.w = tile[ch + 3][w];
    } else {
      v.x = v.y = v.z = v.w = 0;
    }
    o4[((size_t)((c8 * 32 + b) * 58 + h) * 58 + w) * 2 + hf] = v;
  }
}

// ---------------- main implicit-GEMM kernel (m201-style 8-phase) ----------------
// C[cout][pix] = sum_k Wb[cout][k] * im2col[k][pix].
// BM=256 x BN=256, BK=64, 18 K-tiles. 512 thr = 8 waves (2M x 4N), per-wave
// 128x64, mfma 16x16x32 bf16.
// LDS = 4 regions x 32KB; region r holds half-K h (=2t+ks, 32 k-chunk) with
// A [kb2=4][cout=256][8] then B [kb2=4][pix=256][8]; r = h & 3.
// Phase P=4t+q (q=(ks,mh)): {ds_read a[4](+b[4] if mh==0); stage unit of half
// (P>>1)+2 (A at even q, B at odd q; 2 loads/thread); s_barrier; lgkmcnt(0);
// setprio(1); 16 MFMA; setprio(0); s_barrier}. vmcnt(4) once per K-tile at q3
// (keeps last 2 phases' loads in flight); region reuse distance = 4 phases.

__global__ __launch_bounds__(512) void conv_mfma(
    const ushort_t* __restrict__ Wb2, const ushort_t* __restrict__ xp2,
    const float* __restrict__ bias, float* __restrict__ out) {
  __shared__ ushort_t lds[65536];                // 128 KB

  const int tid = threadIdx.x;
  const int lane = tid & 63;
  const int wid = tid >> 6;
  const int wm = wid >> 2, wn = wid & 3;          // 2M x 4N wave grid
  const int lg = lane >> 4, lr = lane & 15;
  const int tileN = blockIdx.x;                   // 0..391 (256 pixels)

  // ---- per-thread staging constants ----
  const int rowOff = (tid & 255) * 8;             // shorts
  const int kb2lo = tid >> 8;                     // 0/1
  const ushort_t* bThr;
  {
    int pg = tileN * 256 + (tid & 255);
    int bq = pg / 3136;
    int rem = pg - bq * 3136;
    int hh = rem / 56;
    int ww = rem - hh * 56;
    int pixChunk = (bq * 58 + hh) * 58 + ww;
    bThr = xp2 + ((size_t)kb2lo * PLANE + pixChunk) * 8;
  }

  // fragment-read per-thread bases (shorts)
  const int aBaseT = (lg * 256 + wm * 128 + lr) * 8;
  const int bBaseT = (lg * 256 + wn * 64 + lr) * 8 + 8192;

  auto stageUnit = [&](int hs, int part) {
    int ts = hs >> 1, kss = hs & 1;
    int rs = (hs & 3) * 16384;
    if (part == 0) {
      int base = (ts * 8 + kss * 4) * 2048;
#pragma unroll
      for (int pl = 0; pl < 2; ++pl) {
        int kb2 = pl * 2 + kb2lo;
        __builtin_amdgcn_global_load_lds(
            (const __attribute__((address_space(1))) unsigned int*)(Wb2 + base + kb2 * 2048 + rowOff),
            (__attribute__((address_space(3))) unsigned int*)(lds + rs + kb2 * 2048 + rowOff),
            16, 0, 0);
      }
    } else {
      int pos = ts >> 1;
      int kh = pos / 3, kw = pos - kh * 3;
      size_t off = ((size_t)((ts & 1) * 8 + kss * 4) * PLANE) * 8 + (kh * 58 + kw) * 8;
#pragma unroll
      for (int pl = 0; pl < 2; ++pl) {
        int kb2 = pl * 2 + kb2lo;
        __builtin_amdgcn_global_load_lds(
            (const __attribute__((address_space(1))) unsigned int*)(bThr + off + (size_t)pl * 2 * PLANE * 8),
            (__attribute__((address_space(3))) unsigned int*)(lds + rs + 8192 + kb2 * 2048 + rowOff),
            16, 0, 0);
      }
    }
  };

  f32x4 acc[8][4] = {};
  bf16x8 bfr[4];

#define DO_PHASE(KS, MH)                                                       \
  {                                                                            \
    const int rb = ((2 * t + (KS)) & 3) * 16384;                               \
    if ((MH) == 0) {                                                           \
      _Pragma("unroll")                                                        \
      for (int n = 0; n < 4; ++n)                                              \
        bfr[n] = *(const bf16x8*)(lds + rb + bBaseT + n * 128);                \
    }                                                                          \
    bf16x8 afr[4];                                                             \
    _Pragma("unroll")                                                          \
    for (int i = 0; i < 4; ++i)                                                \
      afr[i] = *(const bf16x8*)(lds + rb + aBaseT + ((MH)*4 + i) * 128);       \
    {                                                                          \
      int hs = 2 * t + (KS) + 2;                                               \
      if (hs < 36) stageUnit(hs, (MH));                                        \
    }                                                                          \
    __builtin_amdgcn_s_barrier();                                              \
    asm volatile("s_waitcnt lgkmcnt(0)" ::: "memory");                         \
    __builtin_amdgcn_s_setprio(1);                                             \
    _Pragma("unroll")                                                          \
    for (int i = 0; i < 4; ++i)                                                \
      _Pragma("unroll")                                                        \
      for (int n = 0; n < 4; ++n)                                              \
        acc[(MH)*4 + i][n] =                                                   \
            __builtin_amdgcn_mfma_f32_16x16x32_bf16(afr[i], bfr[n],            \
                                                    acc[(MH)*4 + i][n], 0, 0, 0); \
    __builtin_amdgcn_s_setprio(0);                                             \
  }

  // ---- prologue: stage halves 0 and 1, drain, sync ----
  stageUnit(0, 0);
  stageUnit(0, 1);
  stageUnit(1, 0);
  stageUnit(1, 1);
  asm volatile("s_waitcnt vmcnt(0)" ::: "memory");
  __builtin_amdgcn_s_barrier();

  for (int t = 0; t < 18; ++t) {
    DO_PHASE(0, 0)
    __builtin_amdgcn_s_barrier();
    DO_PHASE(0, 1)
    __builtin_amdgcn_s_barrier();
    DO_PHASE(1, 0)
    __builtin_amdgcn_s_barrier();
    DO_PHASE(1, 1)
    if (t < 16) {
      asm volatile("s_waitcnt vmcnt(4)" ::: "memory");
    } else if (t == 16) {
      asm volatile("s_waitcnt vmcnt(0)" ::: "memory");
    }
    __builtin_amdgcn_s_barrier();
  }
#undef DO_PHASE

  // ---- epilogue: row = cout = wm*128 + m*16 + lg*4 + r,  col = pix ----
  const int cb = wm * 128 + lg * 4;
  float bvv[8][4];
#pragma unroll
  for (int m = 0; m < 8; ++m)
#pragma unroll
    for (int r = 0; r < 4; ++r) bvv[m][r] = bias[cb + m * 16 + r];

#pragma unroll
  for (int n = 0; n < 4; ++n) {
    int pgo = tileN * 256 + wn * 64 + n * 16 + lr;
    int bq2 = pgo / 3136;
    int rem2 = pgo - bq2 * 3136;
    float* op = out + (size_t)bq2 * 256 * 3136 + rem2;
#pragma unroll
    for (int m = 0; m < 8; ++m)
#pragma unroll
      for (int r = 0; r < 4; ++r)
        op[(size_t)(cb + m * 16 + r) * 3136] = acc[m][n][r] + bvv[m][r];
  }
}

// ---------------- fallback (ws too small): direct fp32 conv ----------------
__global__ void conv_naive(const float* __restrict__ x, const float* __restrict__ Wt,
                           const float* __restrict__ bias, float* __restrict__ out, int total) {
  int idx = blockIdx.x * 256 + threadIdx.x;
  if (idx >= total) return;
  int w = idx % 56;
  int t1 = idx / 56;
  int h = t1 % 56;
  int t2 = t1 / 56;
  int co = t2 % 256;
  int b = t2 / 256;
  float acc = bias[co];
  for (int c = 0; c < 128; ++c)
    for (int kh = 0; kh < 3; ++kh) {
      int ih = h + kh - 1;
      if (ih < 0 || ih >= 56) continue;
      for (int kw = 0; kw < 3; ++kw) {
        int iw = w + kw - 1;
        if (iw < 0 || iw >= 56) continue;
        acc += x[((b * 128 + c) * 56 + ih) * 56 + iw] * Wt[((co * 128 + c) * 3 + kh) * 3 + kw];
      }
    }
  out[idx] = acc;
}

extern "C" void kernel_launch(void* const* d_in, const int* in_sizes, int n_in,
                              void* d_out, int out_size, void* d_ws, size_t ws_size,
                              hipStream_t stream) {
  const float* x = (const float*)d_in[0];
  const float* Wt = (const float*)d_in[1];
  const float* bias = (const float*)d_in[2];
  float* out = (float*)d_out;

  const size_t need = WB_BYTES + XP_BYTES;   // ~28.1 MB
  if (ws_size < need) {
    int total = BATCH * COUT * H * W;
    conv_naive<<<(total + 255) / 256, 256, 0, stream>>>(x, Wt, bias, out, total);
    return;
  }
  ushort_t* Wb2 = (ushort_t*)d_ws;
  ushort_t* xp2 = (ushort_t*)((char*)d_ws + WB_BYTES);

  conv_w<<<1152, 256, 0, stream>>>(Wt, Wb2);
  xpad2<<<32 * 58, 256, 0, stream>>>(x, xp2);
  conv_mfma<<<392, 512, 0, stream>>>(Wb2, xp2, bias, out);
}